// Round 14
// baseline (1346.563 us; speedup 1.0000x reference)
//
#include <hip/hip_runtime.h>

// Problem constants: N=16, C_IN=32, C_OUT=64, H=W=128, D=5, K=800
#define R_SZ    737280           // 16 * 5(u) * 9(v) * 32 * 32
#define Q_SZ    10240000         // 16*800*800
#define P_SZ    819200           // 16*800*64
#define LI_SZ   1024000          // 16*10*80*80
#define W_SZ    4608000          // 16*45*6400

typedef unsigned short u16;
typedef __attribute__((ext_vector_type(8))) short bf16x8;
typedef __attribute__((ext_vector_type(4))) float f32x4;

#define MFMA16(a, b, c) __builtin_amdgcn_mfma_f32_16x16x32_bf16(a, b, c, 0, 0, 0)

__device__ __forceinline__ float alpha_scale(const float* alpha, const float* reg, int n) {
  return alpha[n] * (16384.0f * reg[0] / 800.0f);
}

__device__ __forceinline__ u16 f2bf(float f) {
  union { float f; unsigned u; } v; v.f = f;
  unsigned r = v.u + 0x7FFFu + ((v.u >> 16) & 1u);
  return (u16)(r >> 16);
}
__device__ __forceinline__ float bf2f(u16 h) {
  union { unsigned u; float f; } v; v.u = ((unsigned)h) << 16; return v.f;
}

__device__ __forceinline__ bf16x8 load8(const u16* p) {
  union { uint4 d; bf16x8 v; } u;
  u.d = *(const uint4*)p;
  return u.v;
}

__device__ __forceinline__ bf16x8 build_frag(const unsigned* w, int s) {
  union { unsigned u[4]; bf16x8 v; } f;
  int b = s >> 1;
  if (s & 1) {
    #pragma unroll
    for (int k = 0; k < 4; ++k) f.u[k] = (w[b + k] >> 16) | (w[b + k + 1] << 16);
  } else {
    #pragma unroll
    for (int k = 0; k < 4; ++k) f.u[k] = w[b + k];
  }
  return f.v;
}

// Stage one image row (C channels, 128 px) into an LDS slot, hi/lo split.
__device__ __forceinline__ void stage_row(u16* slot, int partStride,
                                          const float* __restrict__ img,
                                          int C, int r, bool valid,
                                          int tid, int nthr) {
  for (int idx = tid; idx < C * 16; idx += nthr) {
    int c = idx >> 4, m = idx & 15;
    float v[8];
    if (valid) {
      const float* p = img + ((size_t)c * 128 + r) * 128 + m * 8;
      float4 a = *(const float4*)p;
      float4 b = *(const float4*)(p + 4);
      v[0]=a.x; v[1]=a.y; v[2]=a.z; v[3]=a.w; v[4]=b.x; v[5]=b.y; v[6]=b.z; v[7]=b.w;
    } else {
      #pragma unroll
      for (int k = 0; k < 8; ++k) v[k] = 0.0f;
    }
    union { u16 s[8]; uint2 d[2]; } hh, ll;
    #pragma unroll
    for (int k = 0; k < 8; ++k) {
      u16 h = f2bf(v[k]);
      hh.s[k] = h;
      ll.s[k] = f2bf(v[k] - bf2f(h));
    }
    u16* dh = slot + c * 136 + 4 + m * 8;
    *(uint2*)(dh)     = hh.d[0];
    *(uint2*)(dh + 4) = hh.d[1];
    u16* dl = dh + partStride;
    *(uint2*)(dl)     = ll.d[0];
    *(uint2*)(dl + 4) = ll.d[1];
  }
}

#define SLOT_US 8704     // 2 parts * 32 ch * 136
#define PSTR_32 4352
#define YPSTR   8704

// ---- Rpart[n][chunk][u 0..4][dvi 0..8][c2 32][c1 32] (du>=0 only)
__global__ __launch_bounds__(640) void k_corrR_mfma(const float* __restrict__ x,
                                                    float* __restrict__ Rpart) {
  __shared__ __align__(16) u16 lds[5 * SLOT_US];
  int n  = blockIdx.x >> 4;
  int r0 = (blockIdx.x & 15) << 3;
  int tid = threadIdx.x;
  const float* xn = x + (size_t)n * 32 * 128 * 128;

  if (tid < 320) {
    int s = tid / 64, p = (tid >> 5) & 1, c = tid & 31;
    u16* b = lds + s * SLOT_US + p * PSTR_32 + c * 136;
    uint2 z; z.x = 0; z.y = 0;
    *(uint2*)b = z;
    *(uint2*)(b + 132) = z;
  }
  for (int rr = 0; rr < 5; ++rr) {
    int r = r0 + rr;
    stage_row(lds + (r % 5) * SLOT_US, PSTR_32, xn, 32, r, r < 128, tid, 640);
  }

  int wave = tid >> 6, lane = tid & 63;
  int du = wave >> 1, nt = wave & 1;
  int lm = lane & 15, q = lane >> 4;

  f32x4 acc[9][2];
  #pragma unroll
  for (int dvi = 0; dvi < 9; ++dvi)
    #pragma unroll
    for (int mt = 0; mt < 2; ++mt) acc[dvi][mt] = (f32x4){0.f, 0.f, 0.f, 0.f};

  for (int i = r0; i < r0 + 8; ++i) {
    __syncthreads();
    const u16* A  = lds + (i % 5) * SLOT_US;
    const u16* Bp = lds + ((i + du) % 5) * SLOT_US;
    #pragma unroll
    for (int ks = 0; ks < 4; ++ks) {
      int kb = ks * 32 + q * 8;
      bf16x8 af[2][2];
      #pragma unroll
      for (int pa = 0; pa < 2; ++pa)
        #pragma unroll
        for (int mt = 0; mt < 2; ++mt)
          af[pa][mt] = load8(A + pa * PSTR_32 + (mt * 16 + lm) * 136 + 4 + kb);
      #pragma unroll
      for (int pb = 0; pb < 2; ++pb) {
        const u16* wp = Bp + pb * PSTR_32 + (nt * 16 + lm) * 136 + kb;
        uint4 w0 = *(const uint4*)wp;
        uint4 w1 = *(const uint4*)(wp + 8);
        unsigned w[8] = {w0.x, w0.y, w0.z, w0.w, w1.x, w1.y, w1.z, w1.w};
        #pragma unroll
        for (int dvi = 0; dvi < 9; ++dvi) {
          bf16x8 bf = build_frag(w, dvi);
          #pragma unroll
          for (int mt = 0; mt < 2; ++mt)
            #pragma unroll
            for (int pa = 0; pa < 2; ++pa) {
              if (pa == 1 && pb == 1) continue;
              acc[dvi][mt] = MFMA16(af[pa][mt], bf, acc[dvi][mt]);
            }
        }
      }
    }
    __syncthreads();
    if (i + 1 < r0 + 8) {
      int r = i + 5;
      stage_row(lds + (r % 5) * SLOT_US, PSTR_32, xn, 32, r, r < 128, tid, 640);
    }
  }

  float* Rp = Rpart + (size_t)blockIdx.x * 46080;
  #pragma unroll
  for (int dvi = 0; dvi < 9; ++dvi)
    #pragma unroll
    for (int mt = 0; mt < 2; ++mt) {
      float* dst = Rp + (du * 9 + dvi) * 1024 + (nt * 16 + lm) * 32 + mt * 16 + q * 4;
      *(f32x4*)dst = acc[dvi][mt];
    }
}

__global__ void k_reduceR(const float* __restrict__ part, float* __restrict__ R) {
  int idx = blockIdx.x * 256 + threadIdx.x;
  int n = idx / 46080, rem = idx % 46080;
  const float* p = part + (size_t)n * 16 * 46080 + rem;
  float s = 0.0f;
  #pragma unroll
  for (int c = 0; c < 16; ++c) s += p[(size_t)c * 46080];
  R[idx] = s;
}

// ---- Ppart[n][chunk][ae 25][ci 32][co 64]
__global__ __launch_bounds__(640) void k_corrP_mfma(const float* __restrict__ x,
                                                    const float* __restrict__ y,
                                                    float* __restrict__ Ppart) {
  __shared__ __align__(16) u16 xs[5 * SLOT_US];
  __shared__ __align__(16) u16 ys[2 * YPSTR];
  int n  = blockIdx.x >> 4;
  int r0 = (blockIdx.x & 15) << 3;
  int tid = threadIdx.x;
  const float* xn = x + (size_t)n * 32 * 128 * 128;
  const float* yn = y + (size_t)n * 64 * 128 * 128;

  if (tid < 320) {
    int s = tid / 64, p = (tid >> 5) & 1, c = tid & 31;
    u16* b = xs + s * SLOT_US + p * PSTR_32 + c * 136;
    uint2 z; z.x = 0; z.y = 0;
    *(uint2*)b = z;
    *(uint2*)(b + 132) = z;
  }
  for (int rr = -2; rr <= 2; ++rr) {
    int r = r0 + rr;
    stage_row(xs + ((r + 10) % 5) * SLOT_US, PSTR_32, xn, 32, r,
              (r >= 0 && r < 128), tid, 640);
  }
  stage_row(ys, YPSTR, yn, 64, r0, true, tid, 640);

  int wave = tid >> 6, lane = tid & 63;
  int du = (wave >> 1) - 2, mh = wave & 1;
  int lm = lane & 15, q = lane >> 4;

  f32x4 acc[5][2][2];
  #pragma unroll
  for (int dvi = 0; dvi < 5; ++dvi)
    #pragma unroll
    for (int mt = 0; mt < 2; ++mt)
      #pragma unroll
      for (int nt = 0; nt < 2; ++nt)
        acc[dvi][mt][nt] = (f32x4){0.f, 0.f, 0.f, 0.f};

  for (int i = r0; i < r0 + 8; ++i) {
    __syncthreads();
    const u16* Bp = xs + ((i + du + 10) % 5) * SLOT_US;
    #pragma unroll
    for (int ks = 0; ks < 4; ++ks) {
      int kb = ks * 32 + q * 8;
      bf16x8 af[2][2];
      #pragma unroll
      for (int pa = 0; pa < 2; ++pa)
        #pragma unroll
        for (int mt = 0; mt < 2; ++mt)
          af[pa][mt] = load8(ys + pa * YPSTR + (mh * 32 + mt * 16 + lm) * 136 + 4 + kb);
      #pragma unroll
      for (int nt = 0; nt < 2; ++nt)
        #pragma unroll
        for (int pb = 0; pb < 2; ++pb) {
          const u16* wp = Bp + pb * PSTR_32 + (nt * 16 + lm) * 136 + kb;
          uint4 w0 = *(const uint4*)wp;
          uint4 w1 = *(const uint4*)(wp + 8);
          unsigned w[8] = {w0.x, w0.y, w0.z, w0.w, w1.x, w1.y, w1.z, w1.w};
          #pragma unroll
          for (int dvi = 0; dvi < 5; ++dvi) {
            bf16x8 bf = build_frag(w, dvi + 2);
            #pragma unroll
            for (int mt = 0; mt < 2; ++mt)
              #pragma unroll
              for (int pa = 0; pa < 2; ++pa) {
                if (pa == 1 && pb == 1) continue;
                acc[dvi][mt][nt] = MFMA16(af[pa][mt], bf, acc[dvi][mt][nt]);
              }
          }
        }
    }
    __syncthreads();
    if (i + 1 < r0 + 8) {
      int r = i + 3;
      stage_row(xs + ((r + 10) % 5) * SLOT_US, PSTR_32, xn, 32, r,
                (r >= 0 && r < 128), tid, 640);
      stage_row(ys, YPSTR, yn, 64, i + 1, true, tid, 640);
    }
  }

  float* Pp = Ppart + (size_t)blockIdx.x * 51200;
  #pragma unroll
  for (int dvi = 0; dvi < 5; ++dvi)
    #pragma unroll
    for (int mt = 0; mt < 2; ++mt)
      #pragma unroll
      for (int nt = 0; nt < 2; ++nt) {
        float* dst = Pp + ((du + 2) * 5 + dvi) * 2048 + (nt * 16 + lm) * 64
                        + mh * 32 + mt * 16 + q * 4;
        *(f32x4*)dst = acc[dvi][mt][nt];
      }
}

__global__ void k_reduceP(const float* __restrict__ part, const float* __restrict__ d,
                          const float* __restrict__ alpha, const float* __restrict__ reg,
                          float* __restrict__ P) {
  int idx = blockIdx.x * 256 + threadIdx.x;
  int n = idx / 51200, rem = idx % 51200;
  int k = rem >> 6, co = rem & 63;
  int ci = k / 25, ae = k % 25;
  const float* p = part + (size_t)n * 16 * 51200 + (ae * 32 + ci) * 64 + co;
  float s = 0.0f;
  #pragma unroll
  for (int c = 0; c < 16; ++c) s += p[(size_t)c * 51200];
  float a = alpha_scale(alpha, reg, n);
  P[idx] = s + a * d[((size_t)n * 64 + co) * 800 + k];
}

// -------- Q build (symmetric R lookup) --------
__global__ void k_buildQ(const float* __restrict__ R, float* __restrict__ Q,
                         const float* __restrict__ alpha, const float* __restrict__ reg) {
  int bid = blockIdx.x;
  int n = bid / 800, k1 = bid % 800;
  int c1 = k1 / 25, r1 = k1 % 25, a = r1 / 5, e = r1 % 5;
  float av = alpha_scale(alpha, reg, n);
  const float* Rn = R + (size_t)n * 45 * 1024;
  float* Qrow = Q + ((size_t)n * 800 + k1) * 800;
  for (int k2 = threadIdx.x; k2 < 800; k2 += 256) {
    int c2 = k2 / 25, r2 = k2 % 25, b = r2 / 5, f = r2 % 5;
    int du = b - a, dv = f - e;
    float v = (du >= 0)
      ? Rn[(du * 9 + dv + 4) * 1024 + c2 * 32 + c1]
      : Rn[((-du) * 9 + 4 - dv) * 1024 + c1 * 32 + c2];
    if (k2 == k1) v += av;
    Qrow[k2] = v;
  }
}

// ======================= Cholesky =======================
// DS back to 82: r13 measured DS=81 (2 blocks/CU for trail) as noise-level,
// and float2 k-loads need an EVEN row stride for 8B-aligned ds_read_b64.
// This round isolates r3's float2-GEMM change (r3 bundled it with a diag
// rewrite and regressed; attribution was never resolved). Mechanism: the
// GEMM inner loops issue 10 ds_read_b32 per k per wave — the dominant
// per-block cost in panel/trail; float2 halves that. Bank check: stride
// 410 floats ≡ 26 (mod 32), gcd=2 -> 2-way alias (free per LDS model).
// diag_factor_invert2 stays byte-identical r2-known-good.
#define DS 82

// acc[5][5] = Arows(5tr..)·Brows(5tc..)^T over k=0..79, float2 k-loads.
__device__ __forceinline__ void gemm5x5(const float* __restrict__ Aa,
                                        const float* __restrict__ Bb,
                                        int tr, int tc, float acc[5][5]) {
  #pragma unroll
  for (int a = 0; a < 5; ++a)
    #pragma unroll
    for (int b = 0; b < 5; ++b) acc[a][b] = 0.0f;
  for (int k = 0; k < 80; k += 2) {
    float2 av[5], bv[5];
    #pragma unroll
    for (int dd = 0; dd < 5; ++dd) {
      av[dd] = *(const float2*)&Aa[(5*tr+dd)*DS + k];
      bv[dd] = *(const float2*)&Bb[(5*tc+dd)*DS + k];
    }
    #pragma unroll
    for (int a = 0; a < 5; ++a)
      #pragma unroll
      for (int b = 0; b < 5; ++b)
        acc[a][b] += av[a].x * bv[b].x + av[a].y * bv[b].y;
  }
}

__device__ void diag_factor_invert2(float* As, float* Bs,
                                    float* __restrict__ Ln, float* __restrict__ LnT,
                                    int tid) {
  __shared__ float Dinv_s[16 * 25];   // 16 per-strip 5x5 lower-tri inverses
  // --- blocked factorization: 16 strips of 5, redundant 5x5 register factor
  for (int s = 0; s < 16; ++s) {
    int b = 5 * s;
    float a[5][5], dinv[5];
    #pragma unroll
    for (int ii = 0; ii < 5; ++ii)
      #pragma unroll
      for (int kk = 0; kk <= ii; ++kk) a[ii][kk] = As[(b+ii)*DS + b+kk];
    #pragma unroll
    for (int jj = 0; jj < 5; ++jj) {
      float dd = sqrtf(a[jj][jj]);
      a[jj][jj] = dd; dinv[jj] = 1.0f / dd;
      #pragma unroll
      for (int ii = jj+1; ii < 5; ++ii) a[ii][jj] *= dinv[jj];
      #pragma unroll
      for (int ii = jj+1; ii < 5; ++ii)
        #pragma unroll
        for (int kk = jj+1; kk <= ii; ++kk) a[ii][kk] -= a[ii][jj] * a[kk][jj];
    }
    if (tid < 25) {
      int ii = tid / 5, kk = tid % 5;
      if (kk <= ii) As[(b+ii)*DS + b+kk] = a[ii][kk];
    }
    int m = 75 - b;
    // panel row solves (each thread one row)
    for (int r = tid; r < m; r += 256) {
      int row = b + 5 + r;
      float w[5];
      #pragma unroll
      for (int c = 0; c < 5; ++c) {
        float av2 = As[row*DS + b + c];
        #pragma unroll
        for (int kk = 0; kk < c; ++kk) av2 -= w[kk] * a[c][kk];
        w[c] = av2 * dinv[c];
      }
      #pragma unroll
      for (int c = 0; c < 5; ++c) As[row*DS + b + c] = w[c];
    }
    __syncthreads();
    // rank-5 trailing update (lower triangle)
    for (int idx = tid; idx < m*m; idx += 256) {
      int ii = idx / m, kk = idx % m;
      if (kk <= ii) {
        int ri = b+5+ii, rk = b+5+kk;
        float acc2 = As[ri*DS + rk];
        #pragma unroll
        for (int c = 0; c < 5; ++c) acc2 -= As[ri*DS + b+c] * As[rk*DS + b+c];
        As[ri*DS + rk] = acc2;
      }
    }
    __syncthreads();
  }

  // --- phase 1: threads 0..15 invert their strip's 5x5 lower-tri diag block
  if (tid < 16) {
    int i = tid;
    const float* Ab = As + (5*i)*DS + 5*i;
    float L5[5][5], Di[5][5];
    #pragma unroll
    for (int r = 0; r < 5; ++r)
      #pragma unroll
      for (int c = 0; c <= r; ++c) L5[r][c] = Ab[r*DS + c];
    #pragma unroll
    for (int c = 0; c < 5; ++c) {
      #pragma unroll
      for (int r = 0; r < c; ++r) Di[r][c] = 0.0f;
      Di[c][c] = 1.0f / L5[c][c];
      #pragma unroll
      for (int r = c+1; r < 5; ++r) {
        float sacc = 0.0f;
        #pragma unroll
        for (int k = c; k < r; ++k) sacc += L5[r][k] * Di[k][c];
        Di[r][c] = -sacc * (1.0f / L5[r][r]);
      }
    }
    #pragma unroll
    for (int r = 0; r < 5; ++r)
      #pragma unroll
      for (int c = 0; c < 5; ++c) Dinv_s[i*25 + r*5 + c] = Di[r][c];
  }
  __syncthreads();

  // --- phase 2: thread j solves column j in 16 strip-steps.
  if (tid < 80) {
    int j = tid;
    for (int i = 0; i < 16; ++i) {
      float bv[5];
      #pragma unroll
      for (int r = 0; r < 5; ++r) bv[r] = (5*i + r == j) ? 1.0f : 0.0f;
      const float* Arow = As + (5*i)*DS;
      #pragma unroll 5
      for (int k = 0; k < 5*i; ++k) {
        float xc = Bs[k*DS + j];
        #pragma unroll
        for (int r = 0; r < 5; ++r) bv[r] -= Arow[r*DS + k] * xc;
      }
      #pragma unroll
      for (int r = 0; r < 5; ++r) {
        float v = 0.0f;
        #pragma unroll
        for (int c = 0; c <= r; ++c) v += Dinv_s[i*25 + r*5 + c] * bv[c];
        Bs[(5*i + r)*DS + j] = v;
      }
    }
  }
  __syncthreads();
  for (int idx = tid; idx < 6400; idx += 256) {
    int r = idx / 80, c = idx % 80;
    float v = (r >= c) ? Bs[r*DS + c] : 0.0f;
    Ln[idx] = v;           // row-major
    LnT[c*80 + r] = v;     // k-major: LnT[k*80+i] = Linv[i][k]
  }
}

__global__ __launch_bounds__(256) void k_diag0(const float* __restrict__ Q,
                                               float* __restrict__ Linv,
                                               float* __restrict__ LinvT) {
  __shared__ float As[80*DS];
  __shared__ float Bs[80*DS];
  int n = blockIdx.x, tid = threadIdx.x;
  const float* Qn = Q + (size_t)n * 640000;
  for (int idx = tid; idx < 6400; idx += 256) {
    int r = idx / 80, c = idx % 80;
    As[r*DS + c] = Qn[r*800 + c];
  }
  __syncthreads();
  diag_factor_invert2(As, Bs, Linv + (size_t)n*10*6400, LinvT + (size_t)n*10*6400, tid);
}

// k_panel: compute each distinct W_u = A_u * Linv_t^T exactly once.
__global__ __launch_bounds__(256) void k_panel(const float* __restrict__ Q,
                                               const float* __restrict__ Linv,
                                               float* __restrict__ Wrm,
                                               float* __restrict__ Wcm,
                                               int t) {
  int nt = 9 - t;
  int n = blockIdx.x / nt;
  int s = blockIdx.x % nt;
  int bu = t + 1 + s;

  __shared__ float Ls[80*DS];
  __shared__ float Aa[80*DS];
  int tid = threadIdx.x, tc = tid & 15, tr = tid >> 4;
  const float* Qn = Q + (size_t)n * 640000;
  const float* Ln = Linv + ((size_t)n*10 + t) * 6400;

  for (int idx = tid; idx < 6400; idx += 256) {
    int r = idx / 80, c = idx % 80;
    Ls[r*DS + c] = Ln[idx];
    Aa[r*DS + c] = Qn[(size_t)(80*bu + r)*800 + 80*t + c];
  }
  __syncthreads();

  float acc[5][5];
  gemm5x5(Aa, Ls, tr, tc, acc);

  int p = t*9 - t*(t-1)/2 + s;
  size_t base = ((size_t)n*45 + p) * 6400;
  #pragma unroll
  for (int a = 0; a < 5; ++a)
    #pragma unroll
    for (int b = 0; b < 5; ++b) {
      Wrm[base + (5*tr+a)*80 + 5*tc+b] = acc[a][b];
      Wcm[base + (5*tc+b)*80 + 5*tr+a] = acc[a][b];
    }
}

// k_trail: A_ij -= W_i W_j^T, W staged from global (coalesced).
// Tile (0,0) then inline-factors diag t+1 (Bs = the unused Wj buffer).
__global__ __launch_bounds__(256) void k_trail(float* __restrict__ Q,
                                               float* __restrict__ Linv,
                                               float* __restrict__ LinvT,
                                               const float* __restrict__ Wrm,
                                               int t) {
  int nt = 9 - t;
  int T = nt * (nt + 1) / 2;
  int n = blockIdx.x / T;
  int rr = blockIdx.x % T;
  int i = 0;
  while (rr >= i + 1) { rr -= i + 1; ++i; }
  int j = rr;
  int bi = t + 1 + i, bj = t + 1 + j;

  __shared__ float Wi[80*DS];
  __shared__ float Wj[80*DS];
  __shared__ float As[80*DS];
  int tid = threadIdx.x, tc = tid & 15, tr = tid >> 4;
  float* Qn = Q + (size_t)n * 640000;
  int pb = t*9 - t*(t-1)/2;
  const float* Wri = Wrm + ((size_t)n*45 + pb + i) * 6400;
  const float* Wrj = Wrm + ((size_t)n*45 + pb + j) * 6400;

  for (int idx = tid; idx < 6400; idx += 256) {
    int r = idx / 80, c = idx % 80;
    Wi[r*DS + c] = Wri[idx];
    As[r*DS + c] = Qn[(size_t)(80*bi + r)*800 + 80*bj + c];
  }
  if (i != j) {
    for (int idx = tid; idx < 6400; idx += 256) {
      int r = idx / 80, c = idx % 80;
      Wj[r*DS + c] = Wrj[idx];
    }
  }
  __syncthreads();

  const float* Wjb = (i != j) ? Wj : Wi;
  float acc[5][5];
  gemm5x5(Wi, Wjb, tr, tc, acc);

  bool special = (i == 0 && j == 0);
  if (!special) {
    #pragma unroll
    for (int a = 0; a < 5; ++a)
      #pragma unroll
      for (int b = 0; b < 5; ++b)
        Qn[(size_t)(80*bi + 5*tr+a)*800 + 80*bj + 5*tc+b] =
          As[(5*tr+a)*DS + 5*tc+b] - acc[a][b];
  } else {
    #pragma unroll
    for (int a = 0; a < 5; ++a)
      #pragma unroll
      for (int b = 0; b < 5; ++b)
        As[(5*tr+a)*DS + 5*tc+b] -= acc[a][b];
    __syncthreads();
    diag_factor_invert2(As, Wj,
                        Linv  + ((size_t)n*10 + t + 1) * 6400,
                        LinvT + ((size_t)n*10 + t + 1) * 6400, tid);
  }
}

// ======== solve: r9-EXACT version (proven ~130us) — frozen ========
#define ZS 20

__device__ __forceinline__ void seg80p(const float* __restrict__ Mcur, int i,
                                       const float* __restrict__ Mnext,
                                       float4 (&A)[8],
                                       const float2 (&zc)[80],
                                       float& a0, float& a1) {
  const float* Ci = Mcur + i * 80;
  const float* Ni = Mnext + i * 80;
  #pragma unroll
  for (int h = 0; h < 20; ++h) {
    float4 v = A[h & 7];
    if (h < 12)      A[h & 7]  = *(const float4*)(Ci + 4 * (h + 8));
    else if (h < 16) A[h - 8]  = *(const float4*)(Ni + 4 * (h - 8));
    else             A[h - 16] = *(const float4*)(Ni + 4 * (h - 16));
    a0 += v.x * zc[4*h].x;     a1 += v.x * zc[4*h].y;
    a0 += v.y * zc[4*h + 1].x; a1 += v.y * zc[4*h + 1].y;
    a0 += v.z * zc[4*h + 2].x; a1 += v.z * zc[4*h + 2].y;
    a0 += v.w * zc[4*h + 3].x; a1 += v.w * zc[4*h + 3].y;
  }
}

__global__ __launch_bounds__(160, 1) void k_solve(const float* __restrict__ Linv,
                                                  const float* __restrict__ LinvT,
                                                  const float* __restrict__ Wrm,
                                                  const float* __restrict__ Wcm,
                                                  const float* __restrict__ P,
                                                  float* __restrict__ out) {
  __shared__ __align__(16) float z2[2 * 800 * 2];   // [cp][k][2] = 12,800 B
  // XCD swizzle (bijective): n = (bid&7)*2 + (sub>>4), qg4 = (sub&15)*4.
  int bid = blockIdx.x;
  int sub = bid >> 3;                        // 0..31
  int n   = (bid & 7) * 2 + (sub >> 4);      // 0..15
  int qg4 = (sub & 15) << 2;                 // 0,4,...,60
  int tid = threadIdx.x;
  int i   = tid % 80;
  int cp  = tid / 80;                 // 0..1
  const float* Lb  = Linv  + (size_t)n * 10 * 6400;
  const float* LTb = LinvT + (size_t)n * 10 * 6400;
  const float* Wr  = Wrm + (size_t)n * 45 * 6400;
  const float* Wc  = Wcm + (size_t)n * 45 * 6400;

  for (int idx = tid; idx < 3200; idx += 160) {
    int k = idx >> 2, cc = idx & 3;
    z2[((cc >> 1) * 800 + k) * 2 + (cc & 1)] =
        P[((size_t)n * 800 + k) * 64 + qg4 + cc];
  }

  float2 zc[80];
  float4 A[8];
  {  // prologue: preload chunks 0..7 of the first M (forward diag t=0)
    const float* Mi = Lb + i * 80;
    #pragma unroll
    for (int q = 0; q < 8; ++q) A[q] = *(const float4*)(Mi + 4 * q);
  }

  // ---------------- forward:  z = L^{-1} P ----------------
  for (int t = 0; t < 10; ++t) {
    __syncthreads();                       // prior trailing writes visible
    int zb = (cp * 800 + 80 * t) * 2;
    #pragma unroll
    for (int m = 0; m < 40; ++m) {
      float4 v = *(const float4*)&z2[zb + 4 * m];
      zc[2*m]     = make_float2(v.x, v.y);
      zc[2*m + 1] = make_float2(v.z, v.w);
    }
    int nseg = 9 - t;
    const float* Mc = Wr + (size_t)(t * 9 - t * (t - 1) / 2) * 6400;
    const float* nxt = (nseg > 0) ? Mc
                      : (t < 9 ? Lb + (t + 1) * 6400 : LTb + 9 * 6400);
    float a0 = 0.f, a1 = 0.f;
    seg80p(Lb + t * 6400, i, nxt, A, zc, a0, a1);  // row i of Linv_t
    __syncthreads();                       // all zc fills (reads of z_t) done
    *(float2*)&z2[(cp * 800 + 80 * t + i) * 2] = make_float2(a0, a1);
    __syncthreads();                       // z_t final
    #pragma unroll
    for (int m = 0; m < 40; ++m) {
      float4 v = *(const float4*)&z2[zb + 4 * m];
      zc[2*m]     = make_float2(v.x, v.y);
      zc[2*m + 1] = make_float2(v.z, v.w);
    }
    for (int s = 0; s < nseg; ++s) {
      const float* nx2 = (s + 1 < nseg) ? Mc + (size_t)(s + 1) * 6400
                                        : Lb + (t + 1) * 6400;  // nseg>0 => t<9
      float b0 = 0.f, b1 = 0.f;
      seg80p(Mc + (size_t)s * 6400, i, nx2, A, zc, b0, b1);  // W[i][k] contig
      float2* zp = (float2*)&z2[(cp * 800 + 80 * (t + 1 + s) + i) * 2];
      float2 v = *zp; v.x -= b0; v.y -= b1; *zp = v;
    }
  }

  // ---------------- backward: D = L^{-T} z ----------------
  for (int t = 9; t >= 0; --t) {
    __syncthreads();
    int zb = (cp * 800 + 80 * t) * 2;
    #pragma unroll
    for (int m = 0; m < 40; ++m) {
      float4 v = *(const float4*)&z2[zb + 4 * m];
      zc[2*m]     = make_float2(v.x, v.y);
      zc[2*m + 1] = make_float2(v.z, v.w);
    }
    const float* nxt;
    if (t > 0) {
      int p0 = (t - 1) * 9 - (t - 1) * (t - 2) / 2;   // u=t-1 panel
      nxt = Wc + (size_t)p0 * 6400;
    } else nxt = Lb;                                   // dummy (valid mem)
    float a0 = 0.f, a1 = 0.f;
    seg80p(LTb + t * 6400, i, nxt, A, zc, a0, a1);     // LnT[i*80+k]
    __syncthreads();
    *(float2*)&z2[(cp * 800 + 80 * t + i) * 2] = make_float2(a0, a1);
    __syncthreads();
    #pragma unroll
    for (int m = 0; m < 40; ++m) {
      float4 v = *(const float4*)&z2[zb + 4 * m];
      zc[2*m]     = make_float2(v.x, v.y);
      zc[2*m + 1] = make_float2(v.z, v.w);
    }
    for (int u = t - 1; u >= 0; --u) {
      int p = u * 9 - u * (u - 1) / 2 + (t - u - 1);
      const float* nx2;
      if (u > 0) {
        int pn = (u - 1) * 9 - (u - 1) * (u - 2) / 2 + (t - u);
        nx2 = Wc + (size_t)pn * 6400;
      } else nx2 = (t > 0) ? LTb + (t - 1) * 6400 : Lb;  // next diag / dummy
      float b0 = 0.f, b1 = 0.f;
      seg80p(Wc + (size_t)p * 6400, i, nx2, A, zc, b0, b1);  // Wcm[i*80+k]
      float2* zp = (float2*)&z2[(cp * 800 + 80 * u + i) * 2];
      float2 v = *zp; v.x -= b0; v.y -= b1; *zp = v;
    }
  }

  __syncthreads();
  for (int idx = tid; idx < 3200; idx += 160) {
    int c = idx / 800, k = idx % 800;
    out[((size_t)n * 64 + qg4 + c) * 800 + k] =
        z2[((c >> 1) * 800 + k) * 2 + (c & 1)];
  }
}

extern "C" void kernel_launch(void* const* d_in, const int* in_sizes, int n_in,
                              void* d_out, int out_size, void* d_ws, size_t ws_size,
                              hipStream_t stream) {
  const float* x     = (const float*)d_in[0];
  const float* d     = (const float*)d_in[1];
  const float* y     = (const float*)d_in[2];
  const float* alpha = (const float*)d_in[3];
  const float* reg   = (const float*)d_in[4];
  float* out = (float*)d_out;
  float* ws  = (float*)d_ws;

  float* R    = ws;                 // R_SZ
  float* Q    = R + R_SZ;           // Q_SZ
  float* P    = Q + Q_SZ;           // P_SZ
  float* Li   = P + P_SZ;           // LI_SZ
  float* part = Li + LI_SZ;         // 13,107,200 floats (corr partials)
  // overlay after k_reduceP (part is dead then): LiT + Wrm + Wcm = 10,240,000
  float* LiT  = part;
  float* Wrm  = part + LI_SZ;
  float* Wcm  = Wrm + W_SZ;

  k_corrR_mfma<<<256, 640, 0, stream>>>(x, part);
  k_reduceR<<<R_SZ / 256, 256, 0, stream>>>(part, R);
  k_corrP_mfma<<<256, 640, 0, stream>>>(x, y, part);
  k_reduceP<<<P_SZ / 256, 256, 0, stream>>>(part, d, alpha, reg, P);
  k_buildQ<<<16 * 800, 256, 0, stream>>>(R, Q, alpha, reg);

  k_diag0<<<16, 256, 0, stream>>>(Q, Li, LiT);
  for (int t = 0; t < 9; ++t) {
    int nt = 9 - t;
    k_panel<<<16 * nt, 256, 0, stream>>>(Q, Li, Wrm, Wcm, t);
    k_trail<<<16 * nt * (nt + 1) / 2, 256, 0, stream>>>(Q, Li, LiT, Wrm, t);
  }

  k_solve<<<16 * 16, 160, 0, stream>>>(Li, LiT, Wrm, Wcm, P, out);
}

// Round 15
// 1303.079 us; speedup vs baseline: 1.0334x; 1.0334x over previous
//
#include <hip/hip_runtime.h>

// Problem constants: N=16, C_IN=32, C_OUT=64, H=W=128, D=5, K=800
#define R_SZ    737280           // 16 * 5(u) * 9(v) * 32 * 32
#define Q_SZ    10240000         // 16*800*800
#define P_SZ    819200           // 16*800*64
#define LI_SZ   1024000          // 16*10*80*80
#define W_SZ    4608000          // 16*45*6400

typedef unsigned short u16;
typedef __attribute__((ext_vector_type(8))) short bf16x8;
typedef __attribute__((ext_vector_type(4))) float f32x4;

#define MFMA16(a, b, c) __builtin_amdgcn_mfma_f32_16x16x32_bf16(a, b, c, 0, 0, 0)

__device__ __forceinline__ float alpha_scale(const float* alpha, const float* reg, int n) {
  return alpha[n] * (16384.0f * reg[0] / 800.0f);
}

__device__ __forceinline__ u16 f2bf(float f) {
  union { float f; unsigned u; } v; v.f = f;
  unsigned r = v.u + 0x7FFFu + ((v.u >> 16) & 1u);
  return (u16)(r >> 16);
}
__device__ __forceinline__ float bf2f(u16 h) {
  union { unsigned u; float f; } v; v.u = ((unsigned)h) << 16; return v.f;
}

__device__ __forceinline__ bf16x8 load8(const u16* p) {
  union { uint4 d; bf16x8 v; } u;
  u.d = *(const uint4*)p;
  return u.v;
}

__device__ __forceinline__ bf16x8 build_frag(const unsigned* w, int s) {
  union { unsigned u[4]; bf16x8 v; } f;
  int b = s >> 1;
  if (s & 1) {
    #pragma unroll
    for (int k = 0; k < 4; ++k) f.u[k] = (w[b + k] >> 16) | (w[b + k + 1] << 16);
  } else {
    #pragma unroll
    for (int k = 0; k < 4; ++k) f.u[k] = w[b + k];
  }
  return f.v;
}

// Stage one image row (C channels, 128 px) into an LDS slot, hi/lo split.
__device__ __forceinline__ void stage_row(u16* slot, int partStride,
                                          const float* __restrict__ img,
                                          int C, int r, bool valid,
                                          int tid, int nthr) {
  for (int idx = tid; idx < C * 16; idx += nthr) {
    int c = idx >> 4, m = idx & 15;
    float v[8];
    if (valid) {
      const float* p = img + ((size_t)c * 128 + r) * 128 + m * 8;
      float4 a = *(const float4*)p;
      float4 b = *(const float4*)(p + 4);
      v[0]=a.x; v[1]=a.y; v[2]=a.z; v[3]=a.w; v[4]=b.x; v[5]=b.y; v[6]=b.z; v[7]=b.w;
    } else {
      #pragma unroll
      for (int k = 0; k < 8; ++k) v[k] = 0.0f;
    }
    union { u16 s[8]; uint2 d[2]; } hh, ll;
    #pragma unroll
    for (int k = 0; k < 8; ++k) {
      u16 h = f2bf(v[k]);
      hh.s[k] = h;
      ll.s[k] = f2bf(v[k] - bf2f(h));
    }
    u16* dh = slot + c * 136 + 4 + m * 8;
    *(uint2*)(dh)     = hh.d[0];
    *(uint2*)(dh + 4) = hh.d[1];
    u16* dl = dh + partStride;
    *(uint2*)(dl)     = ll.d[0];
    *(uint2*)(dl + 4) = ll.d[1];
  }
}

#define SLOT_US 8704     // 2 parts * 32 ch * 136
#define PSTR_32 4352
#define YPSTR   8704

// ---- Rpart[n][chunk][u 0..4][dvi 0..8][c2 32][c1 32] (du>=0 only)
__global__ __launch_bounds__(640) void k_corrR_mfma(const float* __restrict__ x,
                                                    float* __restrict__ Rpart) {
  __shared__ __align__(16) u16 lds[5 * SLOT_US];
  int n  = blockIdx.x >> 4;
  int r0 = (blockIdx.x & 15) << 3;
  int tid = threadIdx.x;
  const float* xn = x + (size_t)n * 32 * 128 * 128;

  if (tid < 320) {
    int s = tid / 64, p = (tid >> 5) & 1, c = tid & 31;
    u16* b = lds + s * SLOT_US + p * PSTR_32 + c * 136;
    uint2 z; z.x = 0; z.y = 0;
    *(uint2*)b = z;
    *(uint2*)(b + 132) = z;
  }
  for (int rr = 0; rr < 5; ++rr) {
    int r = r0 + rr;
    stage_row(lds + (r % 5) * SLOT_US, PSTR_32, xn, 32, r, r < 128, tid, 640);
  }

  int wave = tid >> 6, lane = tid & 63;
  int du = wave >> 1, nt = wave & 1;
  int lm = lane & 15, q = lane >> 4;

  f32x4 acc[9][2];
  #pragma unroll
  for (int dvi = 0; dvi < 9; ++dvi)
    #pragma unroll
    for (int mt = 0; mt < 2; ++mt) acc[dvi][mt] = (f32x4){0.f, 0.f, 0.f, 0.f};

  for (int i = r0; i < r0 + 8; ++i) {
    __syncthreads();
    const u16* A  = lds + (i % 5) * SLOT_US;
    const u16* Bp = lds + ((i + du) % 5) * SLOT_US;
    #pragma unroll
    for (int ks = 0; ks < 4; ++ks) {
      int kb = ks * 32 + q * 8;
      bf16x8 af[2][2];
      #pragma unroll
      for (int pa = 0; pa < 2; ++pa)
        #pragma unroll
        for (int mt = 0; mt < 2; ++mt)
          af[pa][mt] = load8(A + pa * PSTR_32 + (mt * 16 + lm) * 136 + 4 + kb);
      #pragma unroll
      for (int pb = 0; pb < 2; ++pb) {
        const u16* wp = Bp + pb * PSTR_32 + (nt * 16 + lm) * 136 + kb;
        uint4 w0 = *(const uint4*)wp;
        uint4 w1 = *(const uint4*)(wp + 8);
        unsigned w[8] = {w0.x, w0.y, w0.z, w0.w, w1.x, w1.y, w1.z, w1.w};
        #pragma unroll
        for (int dvi = 0; dvi < 9; ++dvi) {
          bf16x8 bf = build_frag(w, dvi);
          #pragma unroll
          for (int mt = 0; mt < 2; ++mt)
            #pragma unroll
            for (int pa = 0; pa < 2; ++pa) {
              if (pa == 1 && pb == 1) continue;
              acc[dvi][mt] = MFMA16(af[pa][mt], bf, acc[dvi][mt]);
            }
        }
      }
    }
    __syncthreads();
    if (i + 1 < r0 + 8) {
      int r = i + 5;
      stage_row(lds + (r % 5) * SLOT_US, PSTR_32, xn, 32, r, r < 128, tid, 640);
    }
  }

  float* Rp = Rpart + (size_t)blockIdx.x * 46080;
  #pragma unroll
  for (int dvi = 0; dvi < 9; ++dvi)
    #pragma unroll
    for (int mt = 0; mt < 2; ++mt) {
      float* dst = Rp + (du * 9 + dvi) * 1024 + (nt * 16 + lm) * 32 + mt * 16 + q * 4;
      *(f32x4*)dst = acc[dvi][mt];
    }
}

__global__ void k_reduceR(const float* __restrict__ part, float* __restrict__ R) {
  int idx = blockIdx.x * 256 + threadIdx.x;
  int n = idx / 46080, rem = idx % 46080;
  const float* p = part + (size_t)n * 16 * 46080 + rem;
  float s = 0.0f;
  #pragma unroll
  for (int c = 0; c < 16; ++c) s += p[(size_t)c * 46080];
  R[idx] = s;
}

// ---- Ppart[n][chunk][ae 25][ci 32][co 64]
__global__ __launch_bounds__(640) void k_corrP_mfma(const float* __restrict__ x,
                                                    const float* __restrict__ y,
                                                    float* __restrict__ Ppart) {
  __shared__ __align__(16) u16 xs[5 * SLOT_US];
  __shared__ __align__(16) u16 ys[2 * YPSTR];
  int n  = blockIdx.x >> 4;
  int r0 = (blockIdx.x & 15) << 3;
  int tid = threadIdx.x;
  const float* xn = x + (size_t)n * 32 * 128 * 128;
  const float* yn = y + (size_t)n * 64 * 128 * 128;

  if (tid < 320) {
    int s = tid / 64, p = (tid >> 5) & 1, c = tid & 31;
    u16* b = xs + s * SLOT_US + p * PSTR_32 + c * 136;
    uint2 z; z.x = 0; z.y = 0;
    *(uint2*)b = z;
    *(uint2*)(b + 132) = z;
  }
  for (int rr = -2; rr <= 2; ++rr) {
    int r = r0 + rr;
    stage_row(xs + ((r + 10) % 5) * SLOT_US, PSTR_32, xn, 32, r,
              (r >= 0 && r < 128), tid, 640);
  }
  stage_row(ys, YPSTR, yn, 64, r0, true, tid, 640);

  int wave = tid >> 6, lane = tid & 63;
  int du = (wave >> 1) - 2, mh = wave & 1;
  int lm = lane & 15, q = lane >> 4;

  f32x4 acc[5][2][2];
  #pragma unroll
  for (int dvi = 0; dvi < 5; ++dvi)
    #pragma unroll
    for (int mt = 0; mt < 2; ++mt)
      #pragma unroll
      for (int nt = 0; nt < 2; ++nt)
        acc[dvi][mt][nt] = (f32x4){0.f, 0.f, 0.f, 0.f};

  for (int i = r0; i < r0 + 8; ++i) {
    __syncthreads();
    const u16* Bp = xs + ((i + du + 10) % 5) * SLOT_US;
    #pragma unroll
    for (int ks = 0; ks < 4; ++ks) {
      int kb = ks * 32 + q * 8;
      bf16x8 af[2][2];
      #pragma unroll
      for (int pa = 0; pa < 2; ++pa)
        #pragma unroll
        for (int mt = 0; mt < 2; ++mt)
          af[pa][mt] = load8(ys + pa * YPSTR + (mh * 32 + mt * 16 + lm) * 136 + 4 + kb);
      #pragma unroll
      for (int nt = 0; nt < 2; ++nt)
        #pragma unroll
        for (int pb = 0; pb < 2; ++pb) {
          const u16* wp = Bp + pb * PSTR_32 + (nt * 16 + lm) * 136 + kb;
          uint4 w0 = *(const uint4*)wp;
          uint4 w1 = *(const uint4*)(wp + 8);
          unsigned w[8] = {w0.x, w0.y, w0.z, w0.w, w1.x, w1.y, w1.z, w1.w};
          #pragma unroll
          for (int dvi = 0; dvi < 5; ++dvi) {
            bf16x8 bf = build_frag(w, dvi + 2);
            #pragma unroll
            for (int mt = 0; mt < 2; ++mt)
              #pragma unroll
              for (int pa = 0; pa < 2; ++pa) {
                if (pa == 1 && pb == 1) continue;
                acc[dvi][mt][nt] = MFMA16(af[pa][mt], bf, acc[dvi][mt][nt]);
              }
          }
        }
    }
    __syncthreads();
    if (i + 1 < r0 + 8) {
      int r = i + 3;
      stage_row(xs + ((r + 10) % 5) * SLOT_US, PSTR_32, xn, 32, r,
                (r >= 0 && r < 128), tid, 640);
      stage_row(ys, YPSTR, yn, 64, i + 1, true, tid, 640);
    }
  }

  float* Pp = Ppart + (size_t)blockIdx.x * 51200;
  #pragma unroll
  for (int dvi = 0; dvi < 5; ++dvi)
    #pragma unroll
    for (int mt = 0; mt < 2; ++mt)
      #pragma unroll
      for (int nt = 0; nt < 2; ++nt) {
        float* dst = Pp + ((du + 2) * 5 + dvi) * 2048 + (nt * 16 + lm) * 64
                        + mh * 32 + mt * 16 + q * 4;
        *(f32x4*)dst = acc[dvi][mt][nt];
      }
}

__global__ void k_reduceP(const float* __restrict__ part, const float* __restrict__ d,
                          const float* __restrict__ alpha, const float* __restrict__ reg,
                          float* __restrict__ P) {
  int idx = blockIdx.x * 256 + threadIdx.x;
  int n = idx / 51200, rem = idx % 51200;
  int k = rem >> 6, co = rem & 63;
  int ci = k / 25, ae = k % 25;
  const float* p = part + (size_t)n * 16 * 51200 + (ae * 32 + ci) * 64 + co;
  float s = 0.0f;
  #pragma unroll
  for (int c = 0; c < 16; ++c) s += p[(size_t)c * 51200];
  float a = alpha_scale(alpha, reg, n);
  P[idx] = s + a * d[((size_t)n * 64 + co) * 800 + k];
}

// -------- Q build (symmetric R lookup) --------
__global__ void k_buildQ(const float* __restrict__ R, float* __restrict__ Q,
                         const float* __restrict__ alpha, const float* __restrict__ reg) {
  int bid = blockIdx.x;
  int n = bid / 800, k1 = bid % 800;
  int c1 = k1 / 25, r1 = k1 % 25, a = r1 / 5, e = r1 % 5;
  float av = alpha_scale(alpha, reg, n);
  const float* Rn = R + (size_t)n * 45 * 1024;
  float* Qrow = Q + ((size_t)n * 800 + k1) * 800;
  for (int k2 = threadIdx.x; k2 < 800; k2 += 256) {
    int c2 = k2 / 25, r2 = k2 % 25, b = r2 / 5, f = r2 % 5;
    int du = b - a, dv = f - e;
    float v = (du >= 0)
      ? Rn[(du * 9 + dv + 4) * 1024 + c2 * 32 + c1]
      : Rn[((-du) * 9 + 4 - dv) * 1024 + c1 * 32 + c2];
    if (k2 == k1) v += av;
    Qrow[k2] = v;
  }
}

// ======================= Cholesky =======================
// r13-exact chol code (DS=81, scalar GEMMs — the 1330us best; r14 proved
// float2 GEMM neutral-to-negative, so panel/trail are NOT LDS-issue-bound).
// NEW this round: XCD-aware block swizzle for k_panel/k_trail (mechanism
// proven in r9's k_solve: 8x FETCH drop). Same-n blocks currently
// round-robin all 8 XCDs so every XCD's L2 refetches every n's W/Linv/Q
// panels; the chunked bijection wgid=(bid&7)*(nwg/8)+(bid>>3) (valid since
// all panel/trail grids are divisible by 8) puts same-n blocks on 1-2 XCDs.
#define DS 81

__device__ void diag_factor_invert2(float* As, float* Bs,
                                    float* __restrict__ Ln, float* __restrict__ LnT,
                                    int tid) {
  __shared__ float Dinv_s[16 * 25];   // 16 per-strip 5x5 lower-tri inverses
  // --- blocked factorization: 16 strips of 5, redundant 5x5 register factor
  for (int s = 0; s < 16; ++s) {
    int b = 5 * s;
    float a[5][5], dinv[5];
    #pragma unroll
    for (int ii = 0; ii < 5; ++ii)
      #pragma unroll
      for (int kk = 0; kk <= ii; ++kk) a[ii][kk] = As[(b+ii)*DS + b+kk];
    #pragma unroll
    for (int jj = 0; jj < 5; ++jj) {
      float dd = sqrtf(a[jj][jj]);
      a[jj][jj] = dd; dinv[jj] = 1.0f / dd;
      #pragma unroll
      for (int ii = jj+1; ii < 5; ++ii) a[ii][jj] *= dinv[jj];
      #pragma unroll
      for (int ii = jj+1; ii < 5; ++ii)
        #pragma unroll
        for (int kk = jj+1; kk <= ii; ++kk) a[ii][kk] -= a[ii][jj] * a[kk][jj];
    }
    if (tid < 25) {
      int ii = tid / 5, kk = tid % 5;
      if (kk <= ii) As[(b+ii)*DS + b+kk] = a[ii][kk];
    }
    int m = 75 - b;
    // panel row solves (each thread one row)
    for (int r = tid; r < m; r += 256) {
      int row = b + 5 + r;
      float w[5];
      #pragma unroll
      for (int c = 0; c < 5; ++c) {
        float av2 = As[row*DS + b + c];
        #pragma unroll
        for (int kk = 0; kk < c; ++kk) av2 -= w[kk] * a[c][kk];
        w[c] = av2 * dinv[c];
      }
      #pragma unroll
      for (int c = 0; c < 5; ++c) As[row*DS + b + c] = w[c];
    }
    __syncthreads();
    // rank-5 trailing update (lower triangle)
    for (int idx = tid; idx < m*m; idx += 256) {
      int ii = idx / m, kk = idx % m;
      if (kk <= ii) {
        int ri = b+5+ii, rk = b+5+kk;
        float acc2 = As[ri*DS + rk];
        #pragma unroll
        for (int c = 0; c < 5; ++c) acc2 -= As[ri*DS + b+c] * As[rk*DS + b+c];
        As[ri*DS + rk] = acc2;
      }
    }
    __syncthreads();
  }

  // --- phase 1: threads 0..15 invert their strip's 5x5 lower-tri diag block
  if (tid < 16) {
    int i = tid;
    const float* Ab = As + (5*i)*DS + 5*i;
    float L5[5][5], Di[5][5];
    #pragma unroll
    for (int r = 0; r < 5; ++r)
      #pragma unroll
      for (int c = 0; c <= r; ++c) L5[r][c] = Ab[r*DS + c];
    #pragma unroll
    for (int c = 0; c < 5; ++c) {
      #pragma unroll
      for (int r = 0; r < c; ++r) Di[r][c] = 0.0f;
      Di[c][c] = 1.0f / L5[c][c];
      #pragma unroll
      for (int r = c+1; r < 5; ++r) {
        float sacc = 0.0f;
        #pragma unroll
        for (int k = c; k < r; ++k) sacc += L5[r][k] * Di[k][c];
        Di[r][c] = -sacc * (1.0f / L5[r][r]);
      }
    }
    #pragma unroll
    for (int r = 0; r < 5; ++r)
      #pragma unroll
      for (int c = 0; c < 5; ++c) Dinv_s[i*25 + r*5 + c] = Di[r][c];
  }
  __syncthreads();

  // --- phase 2: thread j solves column j in 16 strip-steps.
  if (tid < 80) {
    int j = tid;
    for (int i = 0; i < 16; ++i) {
      float bv[5];
      #pragma unroll
      for (int r = 0; r < 5; ++r) bv[r] = (5*i + r == j) ? 1.0f : 0.0f;
      const float* Arow = As + (5*i)*DS;
      #pragma unroll 5
      for (int k = 0; k < 5*i; ++k) {
        float xc = Bs[k*DS + j];
        #pragma unroll
        for (int r = 0; r < 5; ++r) bv[r] -= Arow[r*DS + k] * xc;
      }
      #pragma unroll
      for (int r = 0; r < 5; ++r) {
        float v = 0.0f;
        #pragma unroll
        for (int c = 0; c <= r; ++c) v += Dinv_s[i*25 + r*5 + c] * bv[c];
        Bs[(5*i + r)*DS + j] = v;
      }
    }
  }
  __syncthreads();
  for (int idx = tid; idx < 6400; idx += 256) {
    int r = idx / 80, c = idx % 80;
    float v = (r >= c) ? Bs[r*DS + c] : 0.0f;
    Ln[idx] = v;           // row-major
    LnT[c*80 + r] = v;     // k-major: LnT[k*80+i] = Linv[i][k]
  }
}

__global__ __launch_bounds__(256) void k_diag0(const float* __restrict__ Q,
                                               float* __restrict__ Linv,
                                               float* __restrict__ LinvT) {
  __shared__ float As[80*DS];
  __shared__ float Bs[80*DS];
  int n = blockIdx.x, tid = threadIdx.x;
  const float* Qn = Q + (size_t)n * 640000;
  for (int idx = tid; idx < 6400; idx += 256) {
    int r = idx / 80, c = idx % 80;
    As[r*DS + c] = Qn[r*800 + c];
  }
  __syncthreads();
  diag_factor_invert2(As, Bs, Linv + (size_t)n*10*6400, LinvT + (size_t)n*10*6400, tid);
}

// k_panel: compute each distinct W_u = A_u * Linv_t^T exactly once.
// grid = 16 * nt (divisible by 8), XCD-swizzled so same-n blocks share L2.
__global__ __launch_bounds__(256) void k_panel(const float* __restrict__ Q,
                                               const float* __restrict__ Linv,
                                               float* __restrict__ Wrm,
                                               float* __restrict__ Wcm,
                                               int t) {
  int nt = 9 - t;
  int nwg = 16 * nt;
  int wgid = (blockIdx.x & 7) * (nwg >> 3) + (blockIdx.x >> 3);  // bijective
  int n = wgid / nt;
  int s = wgid % nt;
  int bu = t + 1 + s;

  __shared__ float Ls[80*DS];
  __shared__ float Aa[80*DS];
  int tid = threadIdx.x, tc = tid & 15, tr = tid >> 4;
  const float* Qn = Q + (size_t)n * 640000;
  const float* Ln = Linv + ((size_t)n*10 + t) * 6400;

  for (int idx = tid; idx < 6400; idx += 256) {
    int r = idx / 80, c = idx % 80;
    Ls[r*DS + c] = Ln[idx];
    Aa[r*DS + c] = Qn[(size_t)(80*bu + r)*800 + 80*t + c];
  }
  __syncthreads();

  float acc[5][5];
  #pragma unroll
  for (int a = 0; a < 5; ++a)
    #pragma unroll
    for (int b = 0; b < 5; ++b) acc[a][b] = 0.0f;
  for (int k = 0; k < 80; ++k) {
    float av[5], bv[5];
    #pragma unroll
    for (int dd = 0; dd < 5; ++dd) { av[dd] = Aa[(5*tr+dd)*DS + k]; bv[dd] = Ls[(5*tc+dd)*DS + k]; }
    #pragma unroll
    for (int a = 0; a < 5; ++a)
      #pragma unroll
      for (int b = 0; b < 5; ++b) acc[a][b] += av[a] * bv[b];
  }

  int p = t*9 - t*(t-1)/2 + s;
  size_t base = ((size_t)n*45 + p) * 6400;
  #pragma unroll
  for (int a = 0; a < 5; ++a)
    #pragma unroll
    for (int b = 0; b < 5; ++b) {
      Wrm[base + (5*tr+a)*80 + 5*tc+b] = acc[a][b];
      Wcm[base + (5*tc+b)*80 + 5*tr+a] = acc[a][b];
    }
}

// k_trail: A_ij -= W_i W_j^T, W staged from global (coalesced).
// grid = 16 * T (divisible by 8), XCD-swizzled; same-n blocks share the
// W panels (each W read by ~nt tiles) -> L2 hits instead of 8x refetch.
// Tile (0,0) then inline-factors diag t+1.
__global__ __launch_bounds__(256) void k_trail(float* __restrict__ Q,
                                               float* __restrict__ Linv,
                                               float* __restrict__ LinvT,
                                               const float* __restrict__ Wrm,
                                               int t) {
  int nt = 9 - t;
  int T = nt * (nt + 1) / 2;
  int nwg = 16 * T;
  int wgid = (blockIdx.x & 7) * (nwg >> 3) + (blockIdx.x >> 3);  // bijective
  int n = wgid / T;
  int rr = wgid % T;
  int i = 0;
  while (rr >= i + 1) { rr -= i + 1; ++i; }
  int j = rr;
  int bi = t + 1 + i, bj = t + 1 + j;

  __shared__ float Wi[80*DS];
  __shared__ float Wj[80*DS];
  __shared__ float As[80*DS];
  int tid = threadIdx.x, tc = tid & 15, tr = tid >> 4;
  float* Qn = Q + (size_t)n * 640000;
  int pb = t*9 - t*(t-1)/2;
  const float* Wri = Wrm + ((size_t)n*45 + pb + i) * 6400;
  const float* Wrj = Wrm + ((size_t)n*45 + pb + j) * 6400;

  for (int idx = tid; idx < 6400; idx += 256) {
    int r = idx / 80, c = idx % 80;
    Wi[r*DS + c] = Wri[idx];
    As[r*DS + c] = Qn[(size_t)(80*bi + r)*800 + 80*bj + c];
  }
  if (i != j) {
    for (int idx = tid; idx < 6400; idx += 256) {
      int r = idx / 80, c = idx % 80;
      Wj[r*DS + c] = Wrj[idx];
    }
  }
  __syncthreads();

  const float* Wjb = (i != j) ? Wj : Wi;
  float acc[5][5];
  #pragma unroll
  for (int a = 0; a < 5; ++a)
    #pragma unroll
    for (int b = 0; b < 5; ++b) acc[a][b] = 0.0f;
  for (int k = 0; k < 80; ++k) {
    float av[5], bv[5];
    #pragma unroll
    for (int dd = 0; dd < 5; ++dd) { av[dd] = Wi[(5*tr+dd)*DS + k]; bv[dd] = Wjb[(5*tc+dd)*DS + k]; }
    #pragma unroll
    for (int a = 0; a < 5; ++a)
      #pragma unroll
      for (int b = 0; b < 5; ++b) acc[a][b] += av[a] * bv[b];
  }

  bool special = (i == 0 && j == 0);
  if (!special) {
    #pragma unroll
    for (int a = 0; a < 5; ++a)
      #pragma unroll
      for (int b = 0; b < 5; ++b)
        Qn[(size_t)(80*bi + 5*tr+a)*800 + 80*bj + 5*tc+b] =
          As[(5*tr+a)*DS + 5*tc+b] - acc[a][b];
  } else {
    #pragma unroll
    for (int a = 0; a < 5; ++a)
      #pragma unroll
      for (int b = 0; b < 5; ++b)
        As[(5*tr+a)*DS + 5*tc+b] -= acc[a][b];
    __syncthreads();
    diag_factor_invert2(As, Wj,
                        Linv  + ((size_t)n*10 + t + 1) * 6400,
                        LinvT + ((size_t)n*10 + t + 1) * 6400, tid);
  }
}

// ======== solve: r9-EXACT version (proven ~130us) — frozen ========
#define ZS 20

__device__ __forceinline__ void seg80p(const float* __restrict__ Mcur, int i,
                                       const float* __restrict__ Mnext,
                                       float4 (&A)[8],
                                       const float2 (&zc)[80],
                                       float& a0, float& a1) {
  const float* Ci = Mcur + i * 80;
  const float* Ni = Mnext + i * 80;
  #pragma unroll
  for (int h = 0; h < 20; ++h) {
    float4 v = A[h & 7];
    if (h < 12)      A[h & 7]  = *(const float4*)(Ci + 4 * (h + 8));
    else if (h < 16) A[h - 8]  = *(const float4*)(Ni + 4 * (h - 8));
    else             A[h - 16] = *(const float4*)(Ni + 4 * (h - 16));
    a0 += v.x * zc[4*h].x;     a1 += v.x * zc[4*h].y;
    a0 += v.y * zc[4*h + 1].x; a1 += v.y * zc[4*h + 1].y;
    a0 += v.z * zc[4*h + 2].x; a1 += v.z * zc[4*h + 2].y;
    a0 += v.w * zc[4*h + 3].x; a1 += v.w * zc[4*h + 3].y;
  }
}

__global__ __launch_bounds__(160, 1) void k_solve(const float* __restrict__ Linv,
                                                  const float* __restrict__ LinvT,
                                                  const float* __restrict__ Wrm,
                                                  const float* __restrict__ Wcm,
                                                  const float* __restrict__ P,
                                                  float* __restrict__ out) {
  __shared__ __align__(16) float z2[2 * 800 * 2];   // [cp][k][2] = 12,800 B
  // XCD swizzle (bijective): n = (bid&7)*2 + (sub>>4), qg4 = (sub&15)*4.
  int bid = blockIdx.x;
  int sub = bid >> 3;                        // 0..31
  int n   = (bid & 7) * 2 + (sub >> 4);      // 0..15
  int qg4 = (sub & 15) << 2;                 // 0,4,...,60
  int tid = threadIdx.x;
  int i   = tid % 80;
  int cp  = tid / 80;                 // 0..1
  const float* Lb  = Linv  + (size_t)n * 10 * 6400;
  const float* LTb = LinvT + (size_t)n * 10 * 6400;
  const float* Wr  = Wrm + (size_t)n * 45 * 6400;
  const float* Wc  = Wcm + (size_t)n * 45 * 6400;

  for (int idx = tid; idx < 3200; idx += 160) {
    int k = idx >> 2, cc = idx & 3;
    z2[((cc >> 1) * 800 + k) * 2 + (cc & 1)] =
        P[((size_t)n * 800 + k) * 64 + qg4 + cc];
  }

  float2 zc[80];
  float4 A[8];
  {  // prologue: preload chunks 0..7 of the first M (forward diag t=0)
    const float* Mi = Lb + i * 80;
    #pragma unroll
    for (int q = 0; q < 8; ++q) A[q] = *(const float4*)(Mi + 4 * q);
  }

  // ---------------- forward:  z = L^{-1} P ----------------
  for (int t = 0; t < 10; ++t) {
    __syncthreads();                       // prior trailing writes visible
    int zb = (cp * 800 + 80 * t) * 2;
    #pragma unroll
    for (int m = 0; m < 40; ++m) {
      float4 v = *(const float4*)&z2[zb + 4 * m];
      zc[2*m]     = make_float2(v.x, v.y);
      zc[2*m + 1] = make_float2(v.z, v.w);
    }
    int nseg = 9 - t;
    const float* Mc = Wr + (size_t)(t * 9 - t * (t - 1) / 2) * 6400;
    const float* nxt = (nseg > 0) ? Mc
                      : (t < 9 ? Lb + (t + 1) * 6400 : LTb + 9 * 6400);
    float a0 = 0.f, a1 = 0.f;
    seg80p(Lb + t * 6400, i, nxt, A, zc, a0, a1);  // row i of Linv_t
    __syncthreads();                       // all zc fills (reads of z_t) done
    *(float2*)&z2[(cp * 800 + 80 * t + i) * 2] = make_float2(a0, a1);
    __syncthreads();                       // z_t final
    #pragma unroll
    for (int m = 0; m < 40; ++m) {
      float4 v = *(const float4*)&z2[zb + 4 * m];
      zc[2*m]     = make_float2(v.x, v.y);
      zc[2*m + 1] = make_float2(v.z, v.w);
    }
    for (int s = 0; s < nseg; ++s) {
      const float* nx2 = (s + 1 < nseg) ? Mc + (size_t)(s + 1) * 6400
                                        : Lb + (t + 1) * 6400;  // nseg>0 => t<9
      float b0 = 0.f, b1 = 0.f;
      seg80p(Mc + (size_t)s * 6400, i, nx2, A, zc, b0, b1);  // W[i][k] contig
      float2* zp = (float2*)&z2[(cp * 800 + 80 * (t + 1 + s) + i) * 2];
      float2 v = *zp; v.x -= b0; v.y -= b1; *zp = v;
    }
  }

  // ---------------- backward: D = L^{-T} z ----------------
  for (int t = 9; t >= 0; --t) {
    __syncthreads();
    int zb = (cp * 800 + 80 * t) * 2;
    #pragma unroll
    for (int m = 0; m < 40; ++m) {
      float4 v = *(const float4*)&z2[zb + 4 * m];
      zc[2*m]     = make_float2(v.x, v.y);
      zc[2*m + 1] = make_float2(v.z, v.w);
    }
    const float* nxt;
    if (t > 0) {
      int p0 = (t - 1) * 9 - (t - 1) * (t - 2) / 2;   // u=t-1 panel
      nxt = Wc + (size_t)p0 * 6400;
    } else nxt = Lb;                                   // dummy (valid mem)
    float a0 = 0.f, a1 = 0.f;
    seg80p(LTb + t * 6400, i, nxt, A, zc, a0, a1);     // LnT[i*80+k]
    __syncthreads();
    *(float2*)&z2[(cp * 800 + 80 * t + i) * 2] = make_float2(a0, a1);
    __syncthreads();
    #pragma unroll
    for (int m = 0; m < 40; ++m) {
      float4 v = *(const float4*)&z2[zb + 4 * m];
      zc[2*m]     = make_float2(v.x, v.y);
      zc[2*m + 1] = make_float2(v.z, v.w);
    }
    for (int u = t - 1; u >= 0; --u) {
      int p = u * 9 - u * (u - 1) / 2 + (t - u - 1);
      const float* nx2;
      if (u > 0) {
        int pn = (u - 1) * 9 - (u - 1) * (u - 2) / 2 + (t - u);
        nx2 = Wc + (size_t)pn * 6400;
      } else nx2 = (t > 0) ? LTb + (t - 1) * 6400 : Lb;  // next diag / dummy
      float b0 = 0.f, b1 = 0.f;
      seg80p(Wc + (size_t)p * 6400, i, nx2, A, zc, b0, b1);  // Wcm[i*80+k]
      float2* zp = (float2*)&z2[(cp * 800 + 80 * u + i) * 2];
      float2 v = *zp; v.x -= b0; v.y -= b1; *zp = v;
    }
  }

  __syncthreads();
  for (int idx = tid; idx < 3200; idx += 160) {
    int c = idx / 800, k = idx % 800;
    out[((size_t)n * 64 + qg4 + c) * 800 + k] =
        z2[((c >> 1) * 800 + k) * 2 + (c & 1)];
  }
}

extern "C" void kernel_launch(void* const* d_in, const int* in_sizes, int n_in,
                              void* d_out, int out_size, void* d_ws, size_t ws_size,
                              hipStream_t stream) {
  const float* x     = (const float*)d_in[0];
  const float* d     = (const float*)d_in[1];
  const float* y     = (const float*)d_in[2];
  const float* alpha = (const float*)d_in[3];
  const float* reg   = (const float*)d_in[4];
  float* out = (float*)d_out;
  float* ws  = (float*)d_ws;

  float* R    = ws;                 // R_SZ
  float* Q    = R + R_SZ;           // Q_SZ
  float* P    = Q + Q_SZ;           // P_SZ
  float* Li   = P + P_SZ;           // LI_SZ
  float* part = Li + LI_SZ;         // 13,107,200 floats (corr partials)
  // overlay after k_reduceP (part is dead then): LiT + Wrm + Wcm = 10,240,000
  float* LiT  = part;
  float* Wrm  = part + LI_SZ;
  float* Wcm  = Wrm + W_SZ;

  k_corrR_mfma<<<256, 640, 0, stream>>>(x, part);
  k_reduceR<<<R_SZ / 256, 256, 0, stream>>>(part, R);
  k_corrP_mfma<<<256, 640, 0, stream>>>(x, y, part);
  k_reduceP<<<P_SZ / 256, 256, 0, stream>>>(part, d, alpha, reg, P);
  k_buildQ<<<16 * 800, 256, 0, stream>>>(R, Q, alpha, reg);

  k_diag0<<<16, 256, 0, stream>>>(Q, Li, LiT);
  for (int t = 0; t < 9; ++t) {
    int nt = 9 - t;
    k_panel<<<16 * nt, 256, 0, stream>>>(Q, Li, Wrm, Wcm, t);
    k_trail<<<16 * nt * (nt + 1) / 2, 256, 0, stream>>>(Q, Li, LiT, Wrm, t);
  }

  k_solve<<<16 * 16, 160, 0, stream>>>(Li, LiT, Wrm, Wcm, P, out);
}